// Round 1
// baseline (178.293 us; speedup 1.0000x reference)
//
#include <hip/hip_runtime.h>
#include <hip/hip_bf16.h>
#include <cmath>
#include <stdint.h>

#define B_ 4
#define M_ 1024
#define N_ 2048
#define D_ 1024
#define H_ 16
#define DH_ 64
#define NT 64      // N tile
#define NTILES (N_ / NT)
#define PITCH 72   // prep LDS pitch (bf16)

typedef __bf16 bf16_t;
typedef __attribute__((ext_vector_type(8))) __bf16 bf16x8;
typedef __attribute__((ext_vector_type(16))) float f32x16;

static __device__ __forceinline__ float silu_f(float x) {
  return x / (1.0f + __expf(-x));
}

// pack two f32 -> two bf16 in one u32 (compiler emits v_cvt_pk_bf16_f32)
static __device__ __forceinline__ unsigned pk2(float a, float b) {
  union { __bf16 h[2]; unsigned u; } p;
  p.h[0] = (__bf16)a; p.h[1] = (__bf16)b;
  return p.u;
}

// swap upper 32 lanes of x with lower 32 lanes of y.
// with x==y==v on entry: x becomes lanes[0..31]'s v broadcast to all lanes,
// y becomes lanes[32..63]'s v broadcast to all lanes.
static __device__ __forceinline__ void pl32swap(unsigned &x, unsigned &y) {
  asm volatile("s_nop 0\n\tv_permlane32_swap_b32 %0, %1" : "+v"(x), "+v"(y));
}

// async global->LDS, 16B/lane; LDS dest is wave-uniform base + lane*16
static __device__ __forceinline__ void gload16(const bf16_t* g, bf16_t* l) {
  typedef __attribute__((address_space(1))) const unsigned GU;
  typedef __attribute__((address_space(3))) unsigned LU;
  __builtin_amdgcn_global_load_lds((GU*)(const unsigned*)g, (LU*)(unsigned*)l,
                                   16, 0, 0);
}

// ---- prep: K' = L2norm(silu(kv heads)) [bh][n][d]; Vt = kv^T [bh][d][n] via LDS
//      transpose (coalesced both ways); mask bits packed. ---- (unchanged)
__global__ __launch_bounds__(256) void prep_kernel(
    const float* __restrict__ kv, const int* __restrict__ kv_mask,
    bf16_t* __restrict__ kp, bf16_t* __restrict__ vt,
    unsigned long long* __restrict__ mb) {
  __shared__ __align__(16) bf16_t Lt[NT][PITCH];
  const int bx = blockIdx.x;
  const int hp = bx & 7;
  const int nt = (bx >> 3) & 31;
  const int b  = bx >> 8;
  const int n0 = nt * NT;
  const int tid = threadIdx.x;

  #pragma unroll
  for (int hi = 0; hi < 2; ++hi) {
    const int h = hp * 2 + hi;
    const size_t bh = (size_t)(b * H_ + h);
    {
      const int r = tid >> 2, c0 = (tid & 3) * 16;
      const float* src = kv + ((size_t)(b * N_ + n0 + r)) * D_ + h * DH_ + c0;
      union { float f[16]; float4 v4[4]; } raw;
      raw.v4[0] = *(const float4*)(src + 0);
      raw.v4[1] = *(const float4*)(src + 4);
      raw.v4[2] = *(const float4*)(src + 8);
      raw.v4[3] = *(const float4*)(src + 12);
      float sv[16];
      float ss = 0.f;
      #pragma unroll
      for (int i = 0; i < 16; ++i) { sv[i] = silu_f(raw.f[i]); ss += sv[i] * sv[i]; }
      ss += __shfl_xor(ss, 1); ss += __shfl_xor(ss, 2);
      const float inv = 1.0f / fmaxf(sqrtf(ss), 1e-6f);
      union { bf16_t bs[16]; uint4 u[2]; } pk;
      #pragma unroll
      for (int i = 0; i < 16; ++i) pk.bs[i] = (bf16_t)(sv[i] * inv);
      uint4* kdst = (uint4*)(kp + (bh * N_ + n0 + r) * DH_ + c0);
      kdst[0] = pk.u[0]; kdst[1] = pk.u[1];
      union { bf16_t bs[16]; uint4 u[2]; } pv;
      #pragma unroll
      for (int i = 0; i < 16; ++i) pv.bs[i] = (bf16_t)raw.f[i];
      uint4* ldst = (uint4*)&Lt[r][c0];
      ldst[0] = pv.u[0]; ldst[1] = pv.u[1];
    }
    __syncthreads();
    {
      const int d = tid >> 2, nc = (tid & 3) * 16;
      union { bf16_t bs[16]; uint4 u[2]; } pk;
      #pragma unroll
      for (int i = 0; i < 16; ++i) pk.bs[i] = Lt[nc + i][d];
      uint4* dst = (uint4*)(vt + (bh * DH_ + d) * N_ + n0 + nc);
      dst[0] = pk.u[0]; dst[1] = pk.u[1];
    }
    __syncthreads();
  }
  if (bx == 0 && tid < B_ * (N_ / 64)) {
    const int b2 = tid >> 5, tt = tid & 31;
    unsigned long long m = 0ull;
    for (int i = 0; i < 64; ++i)
      if (kv_mask[b2 * N_ + tt * 64 + i]) m |= (1ull << i);
    mb[tid] = m;
  }
}

// ---- main: flash cross-attn, 32x32x16 MFMA, swapped QK^T (S^T in regs),
//      in-register P via cvt_pk + permlane32_swap, global_load_lds ping-pong
//      staging with XOR-swizzled LDS slots, one barrier per tile. ----
// 4 waves x 32 q-rows = 128 q-rows/block; grid = 4*16*8 = 512
__global__ __launch_bounds__(256, 2) void attn_kernel(
    const float* __restrict__ q, const bf16_t* __restrict__ kp,
    const bf16_t* __restrict__ vt, const unsigned long long* __restrict__ mb,
    float* __restrict__ out) {
  // [row][slot^ (row&7)] swizzle, 8 slots of 8 bf16 per 128B row, no padding
  __shared__ __align__(16) bf16_t Ksh[2][NT * DH_];  // K' tile [n][d]
  __shared__ __align__(16) bf16_t Vsh[2][DH_ * NT];  // V^T tile [d][n]

  const int tid  = threadIdx.x;
  const int w    = tid >> 6;
  const int lane = tid & 63;
  const int l31  = lane & 31;
  const int hi   = lane >> 5;
  const int rho  = l31 & 7;

  // bijective XCD swizzle (512 wgs % 8 == 0): 64 consecutive wgs -> one XCD,
  // so each XCD keeps 8 bh's K/V (4MB) resident in its private L2.
  const int wg = (blockIdx.x & 7) * 64 + (blockIdx.x >> 3);
  const int bh = wg >> 3;
  const int m0 = (wg & 7) * 128;
  const int b = bh >> 4, h = bh & 15;

  const bf16_t* kpb = kp + (size_t)bh * N_ * DH_;
  const bf16_t* vtb = vt + (size_t)bh * DH_ * N_;

  // staging: wave w DMAs rows [w*16, w*16+16) of the 64-row tile, 2 ops each
  // for K and V. LDS dest linear; global source pre-swizzled (slot ^ row&7).
  const int srow  = lane >> 3;             // 0..7
  const int sslot = (lane & 7) ^ srow;     // inverse-swizzled source slot
  const bf16_t* ks0 = kpb + (size_t)(w * 16 + srow) * DH_ + sslot * 8;
  const bf16_t* ks1 = ks0 + 8 * DH_;
  const bf16_t* vs0 = vtb + (size_t)(w * 16 + srow) * N_ + sslot * 8;
  const bf16_t* vs1 = vs0 + 8 * N_;

  // prologue: stage tile 0 into buffer 0 (drained by first barrier)
  gload16(ks0, &Ksh[0][(w * 16) * DH_]);
  gload16(ks1, &Ksh[0][(w * 16 + 8) * DH_]);
  gload16(vs0, &Vsh[0][(w * 16) * NT]);
  gload16(vs1, &Vsh[0][(w * 16 + 8) * NT]);

  // Q: 32 rows/wave straight to registers. Lane (l31,hi) owns row w*32+l31,
  // d = kk*16 + hi*8 + j  (exactly the 32x32x16 B-fragment layout).
  bf16x8 qb[4];
  {
    const float* qrow =
        q + ((size_t)(b * M_ + m0 + w * 32 + l31)) * D_ + h * DH_ + hi * 8;
    float sv[32];
    float ss = 0.f;
    #pragma unroll
    for (int kk = 0; kk < 4; ++kk) {
      float4 a0 = *(const float4*)(qrow + kk * 16);
      float4 a1 = *(const float4*)(qrow + kk * 16 + 4);
      sv[kk * 8 + 0] = silu_f(a0.x); sv[kk * 8 + 1] = silu_f(a0.y);
      sv[kk * 8 + 2] = silu_f(a0.z); sv[kk * 8 + 3] = silu_f(a0.w);
      sv[kk * 8 + 4] = silu_f(a1.x); sv[kk * 8 + 5] = silu_f(a1.y);
      sv[kk * 8 + 6] = silu_f(a1.z); sv[kk * 8 + 7] = silu_f(a1.w);
      #pragma unroll
      for (int i = 0; i < 8; ++i) ss += sv[kk * 8 + i] * sv[kk * 8 + i];
    }
    ss += __shfl_xor(ss, 32);  // partner lane holds the other 32 of the 64 d's
    const float inv = 1.0f / fmaxf(sqrtf(ss), 1e-6f);
    #pragma unroll
    for (int kk = 0; kk < 4; ++kk) {
      union { unsigned u[4]; bf16x8 v; } pq;
      #pragma unroll
      for (int jj = 0; jj < 4; ++jj)
        pq.u[jj] = pk2(sv[kk * 8 + jj * 2] * inv, sv[kk * 8 + jj * 2 + 1] * inv);
      qb[kk] = pq.v;
    }
  }

  // fragment read offsets (loop-invariant): row = i*32+l31, slot = 2*j+hi,
  // swizzled slot' = slot ^ (row&7). Same table serves K (i=nb,j=kk) and
  // V (i=db,j=ks).
  int foff[2][4];
  #pragma unroll
  for (int i = 0; i < 2; ++i)
    #pragma unroll
    for (int j = 0; j < 4; ++j)
      foff[i][j] = (i * 32 + l31) * 64 + ((((j << 1) + hi) ^ rho) << 3);

  f32x16 o0, o1;
  #pragma unroll
  for (int r = 0; r < 16; ++r) { o0[r] = 0.f; o1[r] = 0.f; }
  float lrun = 0.f;
  const unsigned long long* mbb = mb + b * (N_ / 64);
  const float C1 = 0.125f * 1.44269504f;  // exp((s-1)/8) = exp2(s*C1 - C1)

  for (int t = 0; t < NTILES; ++t) {
    // barrier: (a) completes DMA for tile t (implicit vmcnt(0) drain),
    // (b) all waves done reading buf[(t+1)&1] (used at t-1) -> safe to restage
    __syncthreads();
    const int cur = t & 1;
    if (t + 1 < NTILES) {
      const int nxt = cur ^ 1;
      const size_t ko = (size_t)(t + 1) * NT * DH_;
      const size_t vo = (size_t)(t + 1) * NT;
      gload16(ks0 + ko, &Ksh[nxt][(w * 16) * DH_]);
      gload16(ks1 + ko, &Ksh[nxt][(w * 16 + 8) * DH_]);
      gload16(vs0 + vo, &Vsh[nxt][(w * 16) * NT]);
      gload16(vs1 + vo, &Vsh[nxt][(w * 16 + 8) * NT]);
    }
    const unsigned long long mk = mbb[t];
    const bf16_t* Kc = Ksh[cur];
    const bf16_t* Vc = Vsh[cur];

    bf16x8 pa[4];
    #pragma unroll
    for (int nb = 0; nb < 2; ++nb) {
      // S^T = K' Q'^T : C[row=n][col=m], col = l31, row = (r&3)+8*(r>>2)+4*hi
      f32x16 s;
      #pragma unroll
      for (int r = 0; r < 16; ++r) s[r] = 0.f;
      __builtin_amdgcn_s_setprio(1);
      #pragma unroll
      for (int kk = 0; kk < 4; ++kk) {
        bf16x8 ka = *(const bf16x8*)(Kc + foff[nb][kk]);
        s = __builtin_amdgcn_mfma_f32_32x32x16_bf16(ka, qb[kk], s, 0, 0, 0);
      }
      __builtin_amdgcn_s_setprio(0);

      // fixed-max softmax: unit q',k' => |s|<=1; p = exp((s-1)/8), exact after
      // the l-division. Mask bit n = (r&3)+8*(r>>2)+4*hi + 32*nb.
      const unsigned um = (unsigned)(mk >> (nb * 32 + (hi << 2)));
      float p[16];
      #pragma unroll
      for (int r = 0; r < 16; ++r) {
        const float e = exp2f(s[r] * C1 - C1);
        p[r] = ((um >> ((r & 3) + ((r >> 2) << 3))) & 1u) ? 0.f : e;
      }
      lrun += (((p[0] + p[1]) + (p[2] + p[3])) + ((p[4] + p[5]) + (p[6] + p[7]))) +
              (((p[8] + p[9]) + (p[10] + p[11])) + ((p[12] + p[13]) + (p[14] + p[15])));

      // in-register P -> PV A-fragments: pack pairs, exchange halves across the
      // lane<32 / lane>=32 split. A-frag (lane l31,hi) needs
      // P[l31][ks*16 + hi*8 + j]: j<4 lives in the hi=0 lane's regs q=2*tt+hi,
      // j>=4 in the hi=1 lane's same q.
      unsigned pkw[4][2];
      #pragma unroll
      for (int qq = 0; qq < 4; ++qq) {
        pkw[qq][0] = pk2(p[qq * 4 + 0], p[qq * 4 + 1]);
        pkw[qq][1] = pk2(p[qq * 4 + 2], p[qq * 4 + 3]);
      }
      #pragma unroll
      for (int tt = 0; tt < 2; ++tt) {
        union { unsigned u[4]; bf16x8 v; } fr;
        #pragma unroll
        for (int ww = 0; ww < 2; ++ww) {
          const unsigned own = hi ? pkw[2 * tt + 1][ww] : pkw[2 * tt][ww];
          unsigned x = hi ? pkw[2 * tt][ww] : pkw[2 * tt + 1][ww];  // send other's q
          unsigned y = x;
          pl32swap(x, y);                 // x = hi0-lane's val, y = hi1-lane's val
          fr.u[ww]     = hi ? x : own;    // j = 0..3 words
          fr.u[2 + ww] = hi ? own : y;    // j = 4..7 words
        }
        pa[nb * 2 + tt] = fr.v;
      }
    }

    // O += P V : A = pa[ks] (P[m][n16-block ks]), B = V[n][d] from V^T tile
    __builtin_amdgcn_s_setprio(1);
    #pragma unroll
    for (int ks = 0; ks < 4; ++ks) {
      bf16x8 vb0 = *(const bf16x8*)(Vc + foff[0][ks]);
      bf16x8 vb1 = *(const bf16x8*)(Vc + foff[1][ks]);
      o0 = __builtin_amdgcn_mfma_f32_32x32x16_bf16(pa[ks], vb0, o0, 0, 0, 0);
      o1 = __builtin_amdgcn_mfma_f32_32x32x16_bf16(pa[ks], vb1, o1, 0, 0, 0);
    }
    __builtin_amdgcn_s_setprio(0);
  }

  // epilogue: total l per q-row (col l31) lives split across hi halves
  lrun += __shfl_xor(lrun, 32);
  #pragma unroll
  for (int r = 0; r < 16; ++r) {
    const int mrow = (r & 3) + ((r >> 2) << 3) + (hi << 2);
    const float lv = __shfl(lrun, mrow);   // lane mrow holds row mrow's total
    const float iv = lv > 0.f ? 1.0f / lv : 0.f;
    const size_t base =
        ((size_t)(b * M_ + m0 + w * 32 + mrow)) * D_ + h * DH_ + l31;
    out[base]      = o0[r] * iv;
    out[base + 32] = o1[r] * iv;
  }
}

extern "C" void kernel_launch(void* const* d_in, const int* in_sizes, int n_in,
                              void* d_out, int out_size, void* d_ws, size_t ws_size,
                              hipStream_t stream) {
  const float* q  = (const float*)d_in[0];
  const float* kv = (const float*)d_in[1];
  const int* kv_mask = (const int*)d_in[2];
  float* out = (float*)d_out;

  // ws layout: K' 16MB | Vt 16MB | maskbits 1KB
  bf16_t* kp = (bf16_t*)d_ws;
  bf16_t* vt = kp + (size_t)B_ * H_ * N_ * DH_;
  unsigned long long* mb =
      (unsigned long long*)((char*)d_ws + 2 * (size_t)B_ * H_ * N_ * DH_ * sizeof(bf16_t));

  prep_kernel<<<B_ * 32 * 8, 256, 0, stream>>>(kv, kv_mask, kp, vt, mb);
  attn_kernel<<<B_ * H_ * (M_ / 128), 256, 0, stream>>>(q, kp, vt, mb, out);
}

// Round 2
// 169.007 us; speedup vs baseline: 1.0549x; 1.0549x over previous
//
#include <hip/hip_runtime.h>
#include <hip/hip_bf16.h>
#include <cmath>
#include <stdint.h>

#define B_ 4
#define M_ 1024
#define N_ 2048
#define D_ 1024
#define H_ 16
#define DH_ 64
#define NT 64      // N tile
#define NTH 16     // tiles per half (N split 2-way inside the block)
#define PITCH 72   // prep LDS pitch (bf16)

typedef __bf16 bf16_t;
typedef __attribute__((ext_vector_type(8))) __bf16 bf16x8;
typedef __attribute__((ext_vector_type(16))) float f32x16;

static __device__ __forceinline__ float silu_f(float x) {
  return x / (1.0f + __expf(-x));
}

// pack two f32 -> two bf16 in one u32 (v_cvt_pk_bf16_f32)
static __device__ __forceinline__ unsigned pk2(float a, float b) {
  union { __bf16 h[2]; unsigned u; } p;
  p.h[0] = (__bf16)a; p.h[1] = (__bf16)b;
  return p.u;
}

// swap upper 32 lanes of x with lower 32 lanes of y (non-volatile: scheduler
// may interleave; s_nop guards the VALU->permlane hazard)
static __device__ __forceinline__ void pl32swap(unsigned &x, unsigned &y) {
  asm("s_nop 0\n\tv_permlane32_swap_b32 %0, %1" : "+v"(x), "+v"(y));
}

// async global->LDS, 16B/lane; LDS dest is wave-uniform base + lane*16
static __device__ __forceinline__ void gload16(const bf16_t* g, bf16_t* l) {
  typedef __attribute__((address_space(1))) const unsigned GU;
  typedef __attribute__((address_space(3))) unsigned LU;
  __builtin_amdgcn_global_load_lds((GU*)(const unsigned*)g, (LU*)(unsigned*)l,
                                   16, 0, 0);
}

// ---- prep: K' = L2norm(silu(kv heads)) [bh][n][d]; Vt = kv^T [bh][d][n] via LDS
//      transpose; mask bits packed. ---- (unchanged, verified)
__global__ __launch_bounds__(256) void prep_kernel(
    const float* __restrict__ kv, const int* __restrict__ kv_mask,
    bf16_t* __restrict__ kp, bf16_t* __restrict__ vt,
    unsigned long long* __restrict__ mb) {
  __shared__ __align__(16) bf16_t Lt[NT][PITCH];
  const int bx = blockIdx.x;
  const int hp = bx & 7;
  const int nt = (bx >> 3) & 31;
  const int b  = bx >> 8;
  const int n0 = nt * NT;
  const int tid = threadIdx.x;

  #pragma unroll
  for (int hi = 0; hi < 2; ++hi) {
    const int h = hp * 2 + hi;
    const size_t bh = (size_t)(b * H_ + h);
    {
      const int r = tid >> 2, c0 = (tid & 3) * 16;
      const float* src = kv + ((size_t)(b * N_ + n0 + r)) * D_ + h * DH_ + c0;
      union { float f[16]; float4 v4[4]; } raw;
      raw.v4[0] = *(const float4*)(src + 0);
      raw.v4[1] = *(const float4*)(src + 4);
      raw.v4[2] = *(const float4*)(src + 8);
      raw.v4[3] = *(const float4*)(src + 12);
      float sv[16];
      float ss = 0.f;
      #pragma unroll
      for (int i = 0; i < 16; ++i) { sv[i] = silu_f(raw.f[i]); ss += sv[i] * sv[i]; }
      ss += __shfl_xor(ss, 1); ss += __shfl_xor(ss, 2);
      const float inv = 1.0f / fmaxf(sqrtf(ss), 1e-6f);
      union { bf16_t bs[16]; uint4 u[2]; } pk;
      #pragma unroll
      for (int i = 0; i < 16; ++i) pk.bs[i] = (bf16_t)(sv[i] * inv);
      uint4* kdst = (uint4*)(kp + (bh * N_ + n0 + r) * DH_ + c0);
      kdst[0] = pk.u[0]; kdst[1] = pk.u[1];
      union { bf16_t bs[16]; uint4 u[2]; } pv;
      #pragma unroll
      for (int i = 0; i < 16; ++i) pv.bs[i] = (bf16_t)raw.f[i];
      uint4* ldst = (uint4*)&Lt[r][c0];
      ldst[0] = pv.u[0]; ldst[1] = pv.u[1];
    }
    __syncthreads();
    {
      const int d = tid >> 2, nc = (tid & 3) * 16;
      union { bf16_t bs[16]; uint4 u[2]; } pk;
      #pragma unroll
      for (int i = 0; i < 16; ++i) pk.bs[i] = Lt[nc + i][d];
      uint4* dst = (uint4*)(vt + (bh * DH_ + d) * N_ + n0 + nc);
      dst[0] = pk.u[0]; dst[1] = pk.u[1];
    }
    __syncthreads();
  }
  if (bx == 0 && tid < B_ * (N_ / 64)) {
    const int b2 = tid >> 5, tt = tid & 31;
    unsigned long long m = 0ull;
    for (int i = 0; i < 64; ++i)
      if (kv_mask[b2 * N_ + tt * 64 + i]) m |= (1ull << i);
    mb[tid] = m;
  }
}

// ---- main: flash cross-attn, 32x32x16 MFMA, swapped QK^T, in-register P,
//      global_load_lds ping-pong staging, intra-block 2-way N-split:
//      8 waves; waves 0-3 do tiles 0-15, waves 4-7 do tiles 16-31 for the
//      SAME 128 q-rows; fixed-max softmax => partials combine as plain sums
//      through LDS at the end. 16 waves/CU = 4/SIMD. ----
__global__ __launch_bounds__(512, 4) void attn_kernel(
    const float* __restrict__ q, const bf16_t* __restrict__ kp,
    const bf16_t* __restrict__ vt, const unsigned long long* __restrict__ mb,
    float* __restrict__ out) {
  // layout: K[half][buf] at (half*2+buf)*8192, V[half][buf] at 32768+...
  // combine phase reuses [0,32768) for O-partials and [32768,33280) for l.
  __shared__ __align__(1024) char smem[65536];

  const int tid  = threadIdx.x;
  const int w    = tid >> 6;     // 0..7
  const int wq   = w & 3;        // q-row group
  const int half = w >> 2;       // N-half
  const int lane = tid & 63;
  const int l31  = lane & 31;
  const int hi   = lane >> 5;
  const int rho  = l31 & 7;

  // bijective XCD swizzle (512 wgs % 8 == 0)
  const int wg = (blockIdx.x & 7) * 64 + (blockIdx.x >> 3);
  const int bh = wg >> 3;
  const int m0 = (wg & 7) * 128;
  const int b = bh >> 4, h = bh & 15;

  const bf16_t* kpb = kp + (size_t)bh * N_ * DH_ + (size_t)half * NTH * NT * DH_;
  const bf16_t* vtb = vt + (size_t)bh * DH_ * N_;

  // staging: wave stages rows [wq*16, wq*16+16) of its half's 64-row tile.
  // LDS dest linear; global source pre-swizzled (slot ^ (row&7)).
  const int srow  = lane >> 3;
  const int sslot = (lane & 7) ^ srow;
  const bf16_t* ks0 = kpb + (size_t)(wq * 16 + srow) * DH_ + sslot * 8;
  const bf16_t* ks1 = ks0 + 8 * DH_;
  const bf16_t* vs0 = vtb + (size_t)(wq * 16 + srow) * N_ + half * NTH * NT + sslot * 8;
  const bf16_t* vs1 = vs0 + 8 * N_;

  // prologue: stage tile 0 of this half into buffer 0
  {
    bf16_t* Kd = (bf16_t*)(smem + (half * 2 + 0) * 8192) + wq * 16 * DH_;
    bf16_t* Vd = (bf16_t*)(smem + 32768 + (half * 2 + 0) * 8192) + wq * 16 * NT;
    gload16(ks0, Kd); gload16(ks1, Kd + 512);
    gload16(vs0, Vd); gload16(vs1, Vd + 512);
  }

  // Q: 32 rows/wave straight to registers (same rows for both halves).
  // Lane (l31,hi) owns row wq*32+l31, d = kk*16 + hi*8 + j (32x32x16 B-frag).
  bf16x8 qb[4];
  {
    const float* qrow =
        q + ((size_t)(b * M_ + m0 + wq * 32 + l31)) * D_ + h * DH_ + hi * 8;
    float sv[32];
    float ss = 0.f;
    #pragma unroll
    for (int kk = 0; kk < 4; ++kk) {
      float4 a0 = *(const float4*)(qrow + kk * 16);
      float4 a1 = *(const float4*)(qrow + kk * 16 + 4);
      sv[kk * 8 + 0] = silu_f(a0.x); sv[kk * 8 + 1] = silu_f(a0.y);
      sv[kk * 8 + 2] = silu_f(a0.z); sv[kk * 8 + 3] = silu_f(a0.w);
      sv[kk * 8 + 4] = silu_f(a1.x); sv[kk * 8 + 5] = silu_f(a1.y);
      sv[kk * 8 + 6] = silu_f(a1.z); sv[kk * 8 + 7] = silu_f(a1.w);
      #pragma unroll
      for (int i = 0; i < 8; ++i) ss += sv[kk * 8 + i] * sv[kk * 8 + i];
    }
    ss += __shfl_xor(ss, 32);
    const float inv = 1.0f / fmaxf(sqrtf(ss), 1e-6f);
    #pragma unroll
    for (int kk = 0; kk < 4; ++kk) {
      union { unsigned u[4]; bf16x8 v; } pq;
      #pragma unroll
      for (int jj = 0; jj < 4; ++jj)
        pq.u[jj] = pk2(sv[kk * 8 + jj * 2] * inv, sv[kk * 8 + jj * 2 + 1] * inv);
      qb[kk] = pq.v;
    }
  }

  // fragment read offsets: row = i*32+l31, slot' = (2j+hi) ^ (row&7)
  int foff[2][4];
  #pragma unroll
  for (int i = 0; i < 2; ++i)
    #pragma unroll
    for (int j = 0; j < 4; ++j)
      foff[i][j] = (i * 32 + l31) * 64 + ((((j << 1) + hi) ^ rho) << 3);

  f32x16 o0, o1;
  #pragma unroll
  for (int r = 0; r < 16; ++r) { o0[r] = 0.f; o1[r] = 0.f; }
  float lrun = 0.f;
  const unsigned long long* mbb = mb + b * (N_ / 64);
  const float C1 = 0.125f * 1.44269504f;  // exp((s-1)/8) = exp2(s*C1 - C1)

  for (int tt = 0; tt < NTH; ++tt) {
    // barrier: (a) drains DMA for tile tt (implicit vmcnt(0)),
    // (b) all waves done reading buf cur^1 -> safe to restage
    __syncthreads();
    const int cur = tt & 1;
    if (tt + 1 < NTH) {
      const int nx = cur ^ 1;
      const size_t ko = (size_t)(tt + 1) * NT * DH_;
      const size_t vo = (size_t)(tt + 1) * NT;
      bf16_t* Kd = (bf16_t*)(smem + (half * 2 + nx) * 8192) + wq * 16 * DH_;
      bf16_t* Vd = (bf16_t*)(smem + 32768 + (half * 2 + nx) * 8192) + wq * 16 * NT;
      gload16(ks0 + ko, Kd); gload16(ks1 + ko, Kd + 512);
      gload16(vs0 + vo, Vd); gload16(vs1 + vo, Vd + 512);
    }
    const unsigned long long mk = mbb[half * NTH + tt];
    const bf16_t* Kc = (const bf16_t*)(smem + (half * 2 + cur) * 8192);
    const bf16_t* Vc = (const bf16_t*)(smem + 32768 + (half * 2 + cur) * 8192);

    bf16x8 pa[4];
    #pragma unroll
    for (int nb = 0; nb < 2; ++nb) {
      // S^T = K' Q'^T : col = l31 (q-row), row = (r&3)+8*(r>>2)+4*hi (n)
      f32x16 s;
      #pragma unroll
      for (int r = 0; r < 16; ++r) s[r] = 0.f;
      __builtin_amdgcn_s_setprio(1);
      #pragma unroll
      for (int kk = 0; kk < 4; ++kk) {
        bf16x8 ka = *(const bf16x8*)(Kc + foff[nb][kk]);
        s = __builtin_amdgcn_mfma_f32_32x32x16_bf16(ka, qb[kk], s, 0, 0, 0);
      }
      __builtin_amdgcn_s_setprio(0);

      // fixed-max softmax: unit q',k' => |s|<=1; p = exp((s-1)/8)
      const unsigned um = (unsigned)(mk >> (nb * 32 + (hi << 2)));
      float p[16];
      #pragma unroll
      for (int r = 0; r < 16; ++r) {
        const float e = exp2f(s[r] * C1 - C1);
        p[r] = ((um >> ((r & 3) + ((r >> 2) << 3))) & 1u) ? 0.f : e;
      }
      lrun += (((p[0] + p[1]) + (p[2] + p[3])) + ((p[4] + p[5]) + (p[6] + p[7]))) +
              (((p[8] + p[9]) + (p[10] + p[11])) + ((p[12] + p[13]) + (p[14] + p[15])));

      // in-register P -> PV A-fragments via cvt_pk + permlane32_swap
      unsigned pkw[4][2];
      #pragma unroll
      for (int qq = 0; qq < 4; ++qq) {
        pkw[qq][0] = pk2(p[qq * 4 + 0], p[qq * 4 + 1]);
        pkw[qq][1] = pk2(p[qq * 4 + 2], p[qq * 4 + 3]);
      }
      #pragma unroll
      for (int tp = 0; tp < 2; ++tp) {
        union { unsigned u[4]; bf16x8 v; } fr;
        #pragma unroll
        for (int ww = 0; ww < 2; ++ww) {
          const unsigned own = hi ? pkw[2 * tp + 1][ww] : pkw[2 * tp][ww];
          unsigned x = hi ? pkw[2 * tp][ww] : pkw[2 * tp + 1][ww];
          unsigned y = x;
          pl32swap(x, y);
          fr.u[ww]     = hi ? x : own;
          fr.u[2 + ww] = hi ? own : y;
        }
        pa[nb * 2 + tp] = fr.v;
      }
    }

    // O += P V
    __builtin_amdgcn_s_setprio(1);
    #pragma unroll
    for (int ks = 0; ks < 4; ++ks) {
      bf16x8 vb0 = *(const bf16x8*)(Vc + foff[0][ks]);
      bf16x8 vb1 = *(const bf16x8*)(Vc + foff[1][ks]);
      o0 = __builtin_amdgcn_mfma_f32_32x32x16_bf16(pa[ks], vb0, o0, 0, 0, 0);
      o1 = __builtin_amdgcn_mfma_f32_32x32x16_bf16(pa[ks], vb1, o1, 0, 0, 0);
    }
    __builtin_amdgcn_s_setprio(0);
  }

  // ---- combine halves through LDS (fixed-max softmax => plain sums) ----
  __syncthreads();  // all K/V reads done; safe to reuse smem
  lrun += __shfl_xor(lrun, 32);  // lane now holds its half's l for row l31
  float* Ob = (float*)smem;                    // [128][64] f32
  float* Lb = (float*)(smem + 32768);          // [128] f32

  if (half == 0) {
    #pragma unroll
    for (int r = 0; r < 16; ++r) {
      const int mrow = (r & 3) + ((r >> 2) << 3) + (hi << 2);
      Ob[(wq * 32 + mrow) * 64 + l31]      = o0[r];
      Ob[(wq * 32 + mrow) * 64 + 32 + l31] = o1[r];
    }
    if (hi == 0) Lb[wq * 32 + l31] = lrun;
  }
  __syncthreads();
  if (half == 1) {
    const float ltot = lrun + Lb[wq * 32 + l31];  // full l for row l31
    #pragma unroll
    for (int r = 0; r < 16; ++r) {
      const int mrow = (r & 3) + ((r >> 2) << 3) + (hi << 2);
      const float lv = __shfl(ltot, mrow);
      const float iv = lv > 0.f ? 1.0f / lv : 0.f;
      const float oa = Ob[(wq * 32 + mrow) * 64 + l31];
      const float oc = Ob[(wq * 32 + mrow) * 64 + 32 + l31];
      const size_t base =
          ((size_t)(b * M_ + m0 + wq * 32 + mrow)) * D_ + h * DH_ + l31;
      out[base]      = (o0[r] + oa) * iv;
      out[base + 32] = (o1[r] + oc) * iv;
    }
  }
}

extern "C" void kernel_launch(void* const* d_in, const int* in_sizes, int n_in,
                              void* d_out, int out_size, void* d_ws, size_t ws_size,
                              hipStream_t stream) {
  const float* q  = (const float*)d_in[0];
  const float* kv = (const float*)d_in[1];
  const int* kv_mask = (const int*)d_in[2];
  float* out = (float*)d_out;

  // ws layout: K' 16MB | Vt 16MB | maskbits 1KB
  bf16_t* kp = (bf16_t*)d_ws;
  bf16_t* vt = kp + (size_t)B_ * H_ * N_ * DH_;
  unsigned long long* mb =
      (unsigned long long*)((char*)d_ws + 2 * (size_t)B_ * H_ * N_ * DH_ * sizeof(bf16_t));

  prep_kernel<<<B_ * 32 * 8, 256, 0, stream>>>(kv, kv_mask, kp, vt, mb);
  attn_kernel<<<B_ * H_ * (M_ / 128), 512, 0, stream>>>(q, kp, vt, mb, out);
}

// Round 3
// 147.323 us; speedup vs baseline: 1.2102x; 1.1472x over previous
//
#include <hip/hip_runtime.h>
#include <hip/hip_bf16.h>
#include <cmath>
#include <stdint.h>

#define B_ 4
#define M_ 1024
#define N_ 2048
#define D_ 1024
#define H_ 16
#define DH_ 64
#define NT 64      // N tile
#define NTH 16     // tiles per half (N split 2-way inside the block)
#define PITCH 72   // prep LDS pitch (bf16)

typedef __bf16 bf16_t;
typedef __attribute__((ext_vector_type(8))) __bf16 bf16x8;
typedef __attribute__((ext_vector_type(16))) float f32x16;

static __device__ __forceinline__ float silu_f(float x) {
  return x / (1.0f + __expf(-x));
}

// raw v_exp_f32 (exp2). Library exp2f goes through OCML's slow fixup path.
#if __has_builtin(__builtin_amdgcn_exp2f)
#define EXP2F(x) __builtin_amdgcn_exp2f(x)
#else
#define EXP2F(x) __expf((x) * 0.69314718056f)
#endif

// pack two f32 -> two bf16 in one u32 (v_cvt_pk_bf16_f32)
static __device__ __forceinline__ unsigned pk2(float a, float b) {
  union { __bf16 h[2]; unsigned u; } p;
  p.h[0] = (__bf16)a; p.h[1] = (__bf16)b;
  return p.u;
}

// swap upper 32 lanes of x with lower 32 lanes of y
static __device__ __forceinline__ void pl32swap(unsigned &x, unsigned &y) {
  asm("s_nop 0\n\tv_permlane32_swap_b32 %0, %1" : "+v"(x), "+v"(y));
}

// async global->LDS, 16B/lane; LDS dest is wave-uniform base + lane*16
static __device__ __forceinline__ void gload16(const bf16_t* g, bf16_t* l) {
  typedef __attribute__((address_space(1))) const unsigned GU;
  typedef __attribute__((address_space(3))) unsigned LU;
  __builtin_amdgcn_global_load_lds((GU*)(const unsigned*)g, (LU*)(unsigned*)l,
                                   16, 0, 0);
}

// ---- prep: K' = L2norm(silu(kv heads)), ZEROED for masked n; Vt = kv^T,
//      ZEROED for masked n; mask bits packed (for the l-count correction).
//      Masked n then contribute s=0 -> p=exp2(0)=1 exactly, PV adds 1*0=0;
//      attn subtracts the integer count of masked n from l. ----
__global__ __launch_bounds__(256) void prep_kernel(
    const float* __restrict__ kv, const int* __restrict__ kv_mask,
    bf16_t* __restrict__ kp, bf16_t* __restrict__ vt,
    unsigned long long* __restrict__ mb) {
  __shared__ __align__(16) bf16_t Lt[NT][PITCH];
  const int bx = blockIdx.x;
  const int hp = bx & 7;
  const int nt = (bx >> 3) & 31;
  const int b  = bx >> 8;
  const int n0 = nt * NT;
  const int tid = threadIdx.x;
  // keep factor for this thread's row (4 threads per row load the same word)
  const float keep = kv_mask[b * N_ + n0 + (tid >> 2)] ? 0.f : 1.f;

  #pragma unroll
  for (int hi = 0; hi < 2; ++hi) {
    const int h = hp * 2 + hi;
    const size_t bh = (size_t)(b * H_ + h);
    {
      const int r = tid >> 2, c0 = (tid & 3) * 16;
      const float* src = kv + ((size_t)(b * N_ + n0 + r)) * D_ + h * DH_ + c0;
      union { float f[16]; float4 v4[4]; } raw;
      raw.v4[0] = *(const float4*)(src + 0);
      raw.v4[1] = *(const float4*)(src + 4);
      raw.v4[2] = *(const float4*)(src + 8);
      raw.v4[3] = *(const float4*)(src + 12);
      float sv[16];
      float ss = 0.f;
      #pragma unroll
      for (int i = 0; i < 16; ++i) { sv[i] = silu_f(raw.f[i]); ss += sv[i] * sv[i]; }
      ss += __shfl_xor(ss, 1); ss += __shfl_xor(ss, 2);
      const float inv = keep / fmaxf(sqrtf(ss), 1e-6f);  // 0 for masked rows
      union { bf16_t bs[16]; uint4 u[2]; } pk;
      #pragma unroll
      for (int i = 0; i < 16; ++i) pk.bs[i] = (bf16_t)(sv[i] * inv);
      uint4* kdst = (uint4*)(kp + (bh * N_ + n0 + r) * DH_ + c0);
      kdst[0] = pk.u[0]; kdst[1] = pk.u[1];
      union { bf16_t bs[16]; uint4 u[2]; } pv;
      #pragma unroll
      for (int i = 0; i < 16; ++i) pv.bs[i] = (bf16_t)(raw.f[i] * keep);
      uint4* ldst = (uint4*)&Lt[r][c0];
      ldst[0] = pv.u[0]; ldst[1] = pv.u[1];
    }
    __syncthreads();
    {
      const int d = tid >> 2, nc = (tid & 3) * 16;
      union { bf16_t bs[16]; uint4 u[2]; } pk;
      #pragma unroll
      for (int i = 0; i < 16; ++i) pk.bs[i] = Lt[nc + i][d];
      uint4* dst = (uint4*)(vt + (bh * DH_ + d) * N_ + n0 + nc);
      dst[0] = pk.u[0]; dst[1] = pk.u[1];
    }
    __syncthreads();
  }
  if (bx == 0 && tid < B_ * (N_ / 64)) {
    const int b2 = tid >> 5, tt = tid & 31;
    unsigned long long m = 0ull;
    for (int i = 0; i < 64; ++i)
      if (kv_mask[b2 * N_ + tt * 64 + i]) m |= (1ull << i);
    mb[tid] = m;
  }
}

// ---- main: flash cross-attn, 32x32x16 MFMA, swapped QK^T, in-register P,
//      global_load_lds ping-pong staging, intra-block 2-way N-split.
//      Softmax: p = exp2(s*C1) (constant shift cancels in o/l); masked n
//      handled algebraically (zeroed K'/V + scalar popcount correction). ----
__global__ __launch_bounds__(512, 4) void attn_kernel(
    const float* __restrict__ q, const bf16_t* __restrict__ kp,
    const bf16_t* __restrict__ vt, const unsigned long long* __restrict__ mb,
    float* __restrict__ out) {
  // layout: K[half][buf] at (half*2+buf)*8192, V[half][buf] at 32768+...
  // combine phase reuses [0,32768) for O-partials and [32768,33280) for l.
  __shared__ __align__(1024) char smem[65536];

  const int tid  = threadIdx.x;
  const int w    = tid >> 6;     // 0..7
  const int wq   = w & 3;        // q-row group
  const int half = w >> 2;       // N-half
  const int lane = tid & 63;
  const int l31  = lane & 31;
  const int hi   = lane >> 5;
  const int rho  = l31 & 7;

  // bijective XCD swizzle (512 wgs % 8 == 0)
  const int wg = (blockIdx.x & 7) * 64 + (blockIdx.x >> 3);
  const int bh = wg >> 3;
  const int m0 = (wg & 7) * 128;
  const int b = bh >> 4, h = bh & 15;

  const bf16_t* kpb = kp + (size_t)bh * N_ * DH_ + (size_t)half * NTH * NT * DH_;
  const bf16_t* vtb = vt + (size_t)bh * DH_ * N_;

  // staging: wave stages rows [wq*16, wq*16+16) of its half's 64-row tile.
  // LDS dest linear; global source pre-swizzled (slot ^ (row&7)).
  const int srow  = lane >> 3;
  const int sslot = (lane & 7) ^ srow;
  const bf16_t* ks0 = kpb + (size_t)(wq * 16 + srow) * DH_ + sslot * 8;
  const bf16_t* ks1 = ks0 + 8 * DH_;
  const bf16_t* vs0 = vtb + (size_t)(wq * 16 + srow) * N_ + half * NTH * NT + sslot * 8;
  const bf16_t* vs1 = vs0 + 8 * N_;

  // prologue: stage tile 0 of this half into buffer 0
  {
    bf16_t* Kd = (bf16_t*)(smem + (half * 2 + 0) * 8192) + wq * 16 * DH_;
    bf16_t* Vd = (bf16_t*)(smem + 32768 + (half * 2 + 0) * 8192) + wq * 16 * NT;
    gload16(ks0, Kd); gload16(ks1, Kd + 512);
    gload16(vs0, Vd); gload16(vs1, Vd + 512);
  }

  // Q: 32 rows/wave straight to registers. Lane (l31,hi) owns row wq*32+l31,
  // d = kk*16 + hi*8 + j (32x32x16 B-frag).
  bf16x8 qb[4];
  {
    const float* qrow =
        q + ((size_t)(b * M_ + m0 + wq * 32 + l31)) * D_ + h * DH_ + hi * 8;
    float sv[32];
    float ss = 0.f;
    #pragma unroll
    for (int kk = 0; kk < 4; ++kk) {
      float4 a0 = *(const float4*)(qrow + kk * 16);
      float4 a1 = *(const float4*)(qrow + kk * 16 + 4);
      sv[kk * 8 + 0] = silu_f(a0.x); sv[kk * 8 + 1] = silu_f(a0.y);
      sv[kk * 8 + 2] = silu_f(a0.z); sv[kk * 8 + 3] = silu_f(a0.w);
      sv[kk * 8 + 4] = silu_f(a1.x); sv[kk * 8 + 5] = silu_f(a1.y);
      sv[kk * 8 + 6] = silu_f(a1.z); sv[kk * 8 + 7] = silu_f(a1.w);
      #pragma unroll
      for (int i = 0; i < 8; ++i) ss += sv[kk * 8 + i] * sv[kk * 8 + i];
    }
    ss += __shfl_xor(ss, 32);
    const float inv = 1.0f / fmaxf(sqrtf(ss), 1e-6f);
    #pragma unroll
    for (int kk = 0; kk < 4; ++kk) {
      union { unsigned u[4]; bf16x8 v; } pq;
      #pragma unroll
      for (int jj = 0; jj < 4; ++jj)
        pq.u[jj] = pk2(sv[kk * 8 + jj * 2] * inv, sv[kk * 8 + jj * 2 + 1] * inv);
      qb[kk] = pq.v;
    }
  }

  // fragment read offsets: row = i*32+l31, slot' = (2j+hi) ^ (row&7)
  int foff[2][4];
  #pragma unroll
  for (int i = 0; i < 2; ++i)
    #pragma unroll
    for (int j = 0; j < 4; ++j)
      foff[i][j] = (i * 32 + l31) * 64 + ((((j << 1) + hi) ^ rho) << 3);

  f32x16 o0, o1;
  #pragma unroll
  for (int r = 0; r < 16; ++r) { o0[r] = 0.f; o1[r] = 0.f; }
  float lrun = 0.f;
  unsigned cl = 0, ch = 0;  // masked-n counts for hi=0 / hi=1 lanes (scalar)
  const unsigned long long* mbb = mb + b * (N_ / 64);
  const float C1 = 0.125f * 1.44269504f;  // p = exp2(s*C1) = e^(s/8)

  for (int tt = 0; tt < NTH; ++tt) {
    // barrier: (a) drains DMA for tile tt (implicit vmcnt(0)),
    // (b) all waves done reading buf cur^1 -> safe to restage
    __syncthreads();
    const int cur = tt & 1;
    if (tt + 1 < NTH) {
      const int nx = cur ^ 1;
      const size_t ko = (size_t)(tt + 1) * NT * DH_;
      const size_t vo = (size_t)(tt + 1) * NT;
      bf16_t* Kd = (bf16_t*)(smem + (half * 2 + nx) * 8192) + wq * 16 * DH_;
      bf16_t* Vd = (bf16_t*)(smem + 32768 + (half * 2 + nx) * 8192) + wq * 16 * NT;
      gload16(ks0 + ko, Kd); gload16(ks1 + ko, Kd + 512);
      gload16(vs0 + vo, Vd); gload16(vs1 + vo, Vd + 512);
    }
    // phantom-mass counts (SALU; mk is uniform). Lane (hi) covers n-bit
    // positions 32*nb + 4*hi + {0..3, 8..11, 16..19, 24..27}.
    const unsigned long long mk = mbb[half * NTH + tt];
    cl += (unsigned)__popcll(mk & 0x0F0F0F0F0F0F0F0FULL);
    ch += (unsigned)__popcll(mk & 0xF0F0F0F0F0F0F0F0ULL);

    const bf16_t* Kc = (const bf16_t*)(smem + (half * 2 + cur) * 8192);
    const bf16_t* Vc = (const bf16_t*)(smem + 32768 + (half * 2 + cur) * 8192);

    bf16x8 pa[4];
    #pragma unroll
    for (int nb = 0; nb < 2; ++nb) {
      // S^T = K' Q'^T : col = l31 (q-row), row = (r&3)+8*(r>>2)+4*hi (n)
      f32x16 s;
      #pragma unroll
      for (int r = 0; r < 16; ++r) s[r] = 0.f;
      __builtin_amdgcn_s_setprio(1);
      #pragma unroll
      for (int kk = 0; kk < 4; ++kk) {
        bf16x8 ka = *(const bf16x8*)(Kc + foff[nb][kk]);
        s = __builtin_amdgcn_mfma_f32_32x32x16_bf16(ka, qb[kk], s, 0, 0, 0);
      }
      __builtin_amdgcn_s_setprio(0);

      // p = exp2(s*C1); masked n have s=0 -> p=1 (counted out via cl/ch)
      float p[16];
      #pragma unroll
      for (int r = 0; r < 16; ++r) p[r] = EXP2F(s[r] * C1);
      lrun += (((p[0] + p[1]) + (p[2] + p[3])) + ((p[4] + p[5]) + (p[6] + p[7]))) +
              (((p[8] + p[9]) + (p[10] + p[11])) + ((p[12] + p[13]) + (p[14] + p[15])));

      // in-register P -> PV A-fragments via cvt_pk + permlane32_swap
      unsigned pkw[4][2];
      #pragma unroll
      for (int qq = 0; qq < 4; ++qq) {
        pkw[qq][0] = pk2(p[qq * 4 + 0], p[qq * 4 + 1]);
        pkw[qq][1] = pk2(p[qq * 4 + 2], p[qq * 4 + 3]);
      }
      #pragma unroll
      for (int tp = 0; tp < 2; ++tp) {
        union { unsigned u[4]; bf16x8 v; } fr;
        #pragma unroll
        for (int ww = 0; ww < 2; ++ww) {
          const unsigned own = hi ? pkw[2 * tp + 1][ww] : pkw[2 * tp][ww];
          unsigned x = hi ? pkw[2 * tp][ww] : pkw[2 * tp + 1][ww];
          unsigned y = x;
          pl32swap(x, y);
          fr.u[ww]     = hi ? x : own;
          fr.u[2 + ww] = hi ? own : y;
        }
        pa[nb * 2 + tp] = fr.v;
      }
    }

    // O += P V
    __builtin_amdgcn_s_setprio(1);
    #pragma unroll
    for (int ks = 0; ks < 4; ++ks) {
      bf16x8 vb0 = *(const bf16x8*)(Vc + foff[0][ks]);
      bf16x8 vb1 = *(const bf16x8*)(Vc + foff[1][ks]);
      o0 = __builtin_amdgcn_mfma_f32_32x32x16_bf16(pa[ks], vb0, o0, 0, 0, 0);
      o1 = __builtin_amdgcn_mfma_f32_32x32x16_bf16(pa[ks], vb1, o1, 0, 0, 0);
    }
    __builtin_amdgcn_s_setprio(0);
  }

  // subtract phantom mass of masked n (p=1 each, exactly), then combine
  lrun -= (float)(hi ? ch : cl);
  __syncthreads();  // all K/V reads done; safe to reuse smem
  lrun += __shfl_xor(lrun, 32);  // lane now holds its half's l for row l31
  float* Ob = (float*)smem;                    // [128][64] f32
  float* Lb = (float*)(smem + 32768);          // [128] f32

  if (half == 0) {
    #pragma unroll
    for (int r = 0; r < 16; ++r) {
      const int mrow = (r & 3) + ((r >> 2) << 3) + (hi << 2);
      Ob[(wq * 32 + mrow) * 64 + l31]      = o0[r];
      Ob[(wq * 32 + mrow) * 64 + 32 + l31] = o1[r];
    }
    if (hi == 0) Lb[wq * 32 + l31] = lrun;
  }
  __syncthreads();
  if (half == 1) {
    const float ltot = lrun + Lb[wq * 32 + l31];  // full l for row l31
    #pragma unroll
    for (int r = 0; r < 16; ++r) {
      const int mrow = (r & 3) + ((r >> 2) << 3) + (hi << 2);
      const float lv = __shfl(ltot, mrow);
      const float iv = lv > 0.f ? 1.0f / lv : 0.f;
      const float oa = Ob[(wq * 32 + mrow) * 64 + l31];
      const float oc = Ob[(wq * 32 + mrow) * 64 + 32 + l31];
      const size_t base =
          ((size_t)(b * M_ + m0 + wq * 32 + mrow)) * D_ + h * DH_ + l31;
      out[base]      = (o0[r] + oa) * iv;
      out[base + 32] = (o1[r] + oc) * iv;
    }
  }
}

extern "C" void kernel_launch(void* const* d_in, const int* in_sizes, int n_in,
                              void* d_out, int out_size, void* d_ws, size_t ws_size,
                              hipStream_t stream) {
  const float* q  = (const float*)d_in[0];
  const float* kv = (const float*)d_in[1];
  const int* kv_mask = (const int*)d_in[2];
  float* out = (float*)d_out;

  // ws layout: K' 16MB | Vt 16MB | maskbits 1KB
  bf16_t* kp = (bf16_t*)d_ws;
  bf16_t* vt = kp + (size_t)B_ * H_ * N_ * DH_;
  unsigned long long* mb =
      (unsigned long long*)((char*)d_ws + 2 * (size_t)B_ * H_ * N_ * DH_ * sizeof(bf16_t));

  prep_kernel<<<B_ * 32 * 8, 256, 0, stream>>>(kv, kv_mask, kp, vt, mb);
  attn_kernel<<<B_ * H_ * (M_ / 128), 512, 0, stream>>>(q, kp, vt, mb, out);
}

// Round 4
// 146.940 us; speedup vs baseline: 1.2134x; 1.0026x over previous
//
#include <hip/hip_runtime.h>
#include <hip/hip_bf16.h>
#include <cmath>
#include <stdint.h>

#define B_ 4
#define M_ 1024
#define N_ 2048
#define D_ 1024
#define H_ 16
#define DH_ 64
#define NT 64      // N tile
#define NTH 16     // tiles per half (N split 2-way inside the block)
#define PITCH 72   // prep LDS pitch (bf16)

typedef __bf16 bf16_t;
typedef __attribute__((ext_vector_type(8))) __bf16 bf16x8;
typedef __attribute__((ext_vector_type(16))) float f32x16;
typedef __attribute__((ext_vector_type(2))) float f32x2;

static __device__ __forceinline__ float silu_f(float x) {
  return x / (1.0f + __expf(-x));
}

// pack two f32 -> two bf16 in one u32 (v_cvt_pk_bf16_f32)
static __device__ __forceinline__ unsigned pk2(float a, float b) {
  union { __bf16 h[2]; unsigned u; } p;
  p.h[0] = (__bf16)a; p.h[1] = (__bf16)b;
  return p.u;
}

// async global->LDS, 16B/lane; LDS dest is wave-uniform base + lane*16
static __device__ __forceinline__ void gload16(const bf16_t* g, bf16_t* l) {
  typedef __attribute__((address_space(1))) const unsigned GU;
  typedef __attribute__((address_space(3))) unsigned LU;
  __builtin_amdgcn_global_load_lds((GU*)(const unsigned*)g, (LU*)(unsigned*)l,
                                   16, 0, 0);
}

// swap bits 2 and 3 of a row index (involution) — K-row permutation so the
// QK^T C-layout registers land directly in PV B-fragment order.
static __device__ __forceinline__ int sw23(int x) {
  return (x & ~12) | ((x & 4) << 1) | ((x & 8) >> 1);
}

// ---- prep: K' = L2norm(silu(kv heads)), ZEROED for masked n; Vt = kv^T,
//      ZEROED for masked n; mask bits packed (for the l-count correction).
//      Masked n contribute s=0 -> p=poly(0)=1 exactly, PV adds 1*0=0;
//      attn subtracts the integer count of masked n from l. ---- (unchanged)
__global__ __launch_bounds__(256) void prep_kernel(
    const float* __restrict__ kv, const int* __restrict__ kv_mask,
    bf16_t* __restrict__ kp, bf16_t* __restrict__ vt,
    unsigned long long* __restrict__ mb) {
  __shared__ __align__(16) bf16_t Lt[NT][PITCH];
  const int bx = blockIdx.x;
  const int hp = bx & 7;
  const int nt = (bx >> 3) & 31;
  const int b  = bx >> 8;
  const int n0 = nt * NT;
  const int tid = threadIdx.x;
  const float keep = kv_mask[b * N_ + n0 + (tid >> 2)] ? 0.f : 1.f;

  #pragma unroll
  for (int hi = 0; hi < 2; ++hi) {
    const int h = hp * 2 + hi;
    const size_t bh = (size_t)(b * H_ + h);
    {
      const int r = tid >> 2, c0 = (tid & 3) * 16;
      const float* src = kv + ((size_t)(b * N_ + n0 + r)) * D_ + h * DH_ + c0;
      union { float f[16]; float4 v4[4]; } raw;
      raw.v4[0] = *(const float4*)(src + 0);
      raw.v4[1] = *(const float4*)(src + 4);
      raw.v4[2] = *(const float4*)(src + 8);
      raw.v4[3] = *(const float4*)(src + 12);
      float sv[16];
      float ss = 0.f;
      #pragma unroll
      for (int i = 0; i < 16; ++i) { sv[i] = silu_f(raw.f[i]); ss += sv[i] * sv[i]; }
      ss += __shfl_xor(ss, 1); ss += __shfl_xor(ss, 2);
      const float inv = keep / fmaxf(sqrtf(ss), 1e-6f);  // 0 for masked rows
      union { bf16_t bs[16]; uint4 u[2]; } pk;
      #pragma unroll
      for (int i = 0; i < 16; ++i) pk.bs[i] = (bf16_t)(sv[i] * inv);
      uint4* kdst = (uint4*)(kp + (bh * N_ + n0 + r) * DH_ + c0);
      kdst[0] = pk.u[0]; kdst[1] = pk.u[1];
      union { bf16_t bs[16]; uint4 u[2]; } pv;
      #pragma unroll
      for (int i = 0; i < 16; ++i) pv.bs[i] = (bf16_t)(raw.f[i] * keep);
      uint4* ldst = (uint4*)&Lt[r][c0];
      ldst[0] = pv.u[0]; ldst[1] = pv.u[1];
    }
    __syncthreads();
    {
      const int d = tid >> 2, nc = (tid & 3) * 16;
      union { bf16_t bs[16]; uint4 u[2]; } pk;
      #pragma unroll
      for (int i = 0; i < 16; ++i) pk.bs[i] = Lt[nc + i][d];
      uint4* dst = (uint4*)(vt + (bh * DH_ + d) * N_ + n0 + nc);
      dst[0] = pk.u[0]; dst[1] = pk.u[1];
    }
    __syncthreads();
  }
  if (bx == 0 && tid < B_ * (N_ / 64)) {
    const int b2 = tid >> 5, tt = tid & 31;
    unsigned long long m = 0ull;
    for (int i = 0; i < 64; ++i)
      if (kv_mask[b2 * N_ + tt * 64 + i]) m |= (1ull << i);
    mb[tid] = m;
  }
}

// ---- main: flash cross-attn, 32x32x16 MFMA, swapped QK^T with K-row
//      permutation (bits 2<->3) so P registers are the PV B-fragment
//      directly (no permlane); PV computes o^T = V^T . P^T; softmax via
//      2-FMA polynomial e^x ~= 1+x+x^2/2 (|x|<=1/8, /8 folded into Q as
//      exact 2^-3); intra-block 2-way N-split; transpose via the existing
//      LDS combine. ----
__global__ __launch_bounds__(512, 4) void attn_kernel(
    const float* __restrict__ q, const bf16_t* __restrict__ kp,
    const bf16_t* __restrict__ vt, const unsigned long long* __restrict__ mb,
    float* __restrict__ out) {
  // layout: K[half][buf] at (half*2+buf)*8192, V[half][buf] at 32768+...
  // combine phase reuses [0,32768) for O^T-partials and [32768,33280) for l.
  __shared__ __align__(1024) char smem[65536];

  const int tid  = threadIdx.x;
  const int w    = tid >> 6;     // 0..7
  const int wq   = w & 3;        // q-row group
  const int half = w >> 2;       // N-half
  const int lane = tid & 63;
  const int l31  = lane & 31;
  const int hi   = lane >> 5;
  const int rho  = l31 & 7;

  // bijective XCD swizzle (512 wgs % 8 == 0)
  const int wg = (blockIdx.x & 7) * 64 + (blockIdx.x >> 3);
  const int bh = wg >> 3;
  const int m0 = (wg & 7) * 128;
  const int b = bh >> 4, h = bh & 15;

  const bf16_t* kpb = kp + (size_t)bh * N_ * DH_ + (size_t)half * NTH * NT * DH_;
  const bf16_t* vtb = vt + (size_t)bh * DH_ * N_;

  // staging: wave stages LDS rows [wq*16, wq*16+16) of its half's 64-row tile.
  // LDS dest linear; global source pre-swizzled in slot (^ row&7) and, for K,
  // pre-permuted in row (sw23) so S^T registers land in PV B-frag order.
  const int srow  = lane >> 3;
  const int sslot = (lane & 7) ^ srow;
  const bf16_t* ks0 = kpb + (size_t)sw23(wq * 16 + srow) * DH_ + sslot * 8;
  const bf16_t* ks1 = kpb + (size_t)sw23(wq * 16 + 8 + srow) * DH_ + sslot * 8;
  const bf16_t* vs0 = vtb + (size_t)(wq * 16 + srow) * N_ + half * NTH * NT + sslot * 8;
  const bf16_t* vs1 = vs0 + 8 * N_;

  // prologue: stage tile 0 of this half into buffer 0
  {
    bf16_t* Kd = (bf16_t*)(smem + (half * 2 + 0) * 8192) + wq * 16 * DH_;
    bf16_t* Vd = (bf16_t*)(smem + 32768 + (half * 2 + 0) * 8192) + wq * 16 * NT;
    gload16(ks0, Kd); gload16(ks1, Kd + 512);
    gload16(vs0, Vd); gload16(vs1, Vd + 512);
  }

  // Q: 32 rows/wave straight to registers, pre-scaled by 1/8 (exact 2^-3)
  // so x = q'.k'/8 comes straight out of the MFMA.
  bf16x8 qb[4];
  {
    const float* qrow =
        q + ((size_t)(b * M_ + m0 + wq * 32 + l31)) * D_ + h * DH_ + hi * 8;
    float sv[32];
    float ss = 0.f;
    #pragma unroll
    for (int kk = 0; kk < 4; ++kk) {
      float4 a0 = *(const float4*)(qrow + kk * 16);
      float4 a1 = *(const float4*)(qrow + kk * 16 + 4);
      sv[kk * 8 + 0] = silu_f(a0.x); sv[kk * 8 + 1] = silu_f(a0.y);
      sv[kk * 8 + 2] = silu_f(a0.z); sv[kk * 8 + 3] = silu_f(a0.w);
      sv[kk * 8 + 4] = silu_f(a1.x); sv[kk * 8 + 5] = silu_f(a1.y);
      sv[kk * 8 + 6] = silu_f(a1.z); sv[kk * 8 + 7] = silu_f(a1.w);
      #pragma unroll
      for (int i = 0; i < 8; ++i) ss += sv[kk * 8 + i] * sv[kk * 8 + i];
    }
    ss += __shfl_xor(ss, 32);
    const float inv = 0.125f / fmaxf(sqrtf(ss), 1e-6f);
    #pragma unroll
    for (int kk = 0; kk < 4; ++kk) {
      union { unsigned u[4]; bf16x8 v; } pq;
      #pragma unroll
      for (int jj = 0; jj < 4; ++jj)
        pq.u[jj] = pk2(sv[kk * 8 + jj * 2] * inv, sv[kk * 8 + jj * 2 + 1] * inv);
      qb[kk] = pq.v;
    }
  }

  // fragment read offsets: row = i*32+l31, slot' = (2j+hi) ^ (row&7)
  int foff[2][4];
  #pragma unroll
  for (int i = 0; i < 2; ++i)
    #pragma unroll
    for (int j = 0; j < 4; ++j)
      foff[i][j] = (i * 32 + l31) * 64 + ((((j << 1) + hi) ^ rho) << 3);

  f32x16 o0, o1, zvec;
  #pragma unroll
  for (int r = 0; r < 16; ++r) { o0[r] = 0.f; o1[r] = 0.f; zvec[r] = 0.f; }
  float lrun = 0.f;
  unsigned cl = 0, ch = 0;  // masked-n counts for hi=0 / hi=1 lanes
  const unsigned long long* mbb = mb + b * (N_ / 64);

  for (int tt = 0; tt < NTH; ++tt) {
    // barrier: (a) drains DMA for tile tt (implicit vmcnt(0)),
    // (b) all waves done reading buf cur^1 -> safe to restage
    __syncthreads();
    const int cur = tt & 1;
    if (tt + 1 < NTH) {
      const int nx = cur ^ 1;
      const size_t ko = (size_t)(tt + 1) * NT * DH_;
      const size_t vo = (size_t)(tt + 1) * NT;
      bf16_t* Kd = (bf16_t*)(smem + (half * 2 + nx) * 8192) + wq * 16 * DH_;
      bf16_t* Vd = (bf16_t*)(smem + 32768 + (half * 2 + nx) * 8192) + wq * 16 * NT;
      gload16(ks0 + ko, Kd); gload16(ks1 + ko, Kd + 512);
      gload16(vs0 + vo, Vd); gload16(vs1 + vo, Vd + 512);
    }
    // phantom-mass counts (uniform -> SALU popcount). With the sw23 K-row
    // permutation, lane hi covers n bits {16c + 8*hi + 0..7}.
    const unsigned long long mk = mbb[half * NTH + tt];
    cl += (unsigned)__popcll(mk & 0x00FF00FF00FF00FFULL);
    ch += (unsigned)__popcll(mk & 0xFF00FF00FF00FF00ULL);

    const bf16_t* Kc = (const bf16_t*)(smem + (half * 2 + cur) * 8192);
    const bf16_t* Vc = (const bf16_t*)(smem + 32768 + (half * 2 + cur) * 8192);

    bf16x8 pa[4];
    #pragma unroll
    for (int nb = 0; nb < 2; ++nb) {
      // S^T = K'(permuted) . Q'^T : col = l31 (q-row m); reg r of lane hi is
      // n_phys = 16*(r>>3) + 8*hi + (r&7)  (within this nb 32-block)
      __builtin_amdgcn_s_setprio(1);
      f32x16 s = __builtin_amdgcn_mfma_f32_32x32x16_bf16(
          *(const bf16x8*)(Kc + foff[nb][0]), qb[0], zvec, 0, 0, 0);
      #pragma unroll
      for (int kk = 1; kk < 4; ++kk) {
        bf16x8 ka = *(const bf16x8*)(Kc + foff[nb][kk]);
        s = __builtin_amdgcn_mfma_f32_32x32x16_bf16(ka, qb[kk], s, 0, 0, 0);
      }
      __builtin_amdgcn_s_setprio(0);

      // p = e^x ~= 1 + x + x^2/2 (|x| <= 1/8; rel err <= 3.3e-4 << bf16 P
      // rounding). poly(0) = 1 EXACTLY -> masked-n algebra intact.
      f32x2 p2[8];
      #pragma unroll
      for (int i = 0; i < 8; ++i) {
        f32x2 x; x.x = s[2 * i]; x.y = s[2 * i + 1];
        f32x2 u = x * 0.5f + 1.0f;
        p2[i] = x * u + 1.0f;
      }
      f32x2 t0 = (p2[0] + p2[1]) + (p2[2] + p2[3]);
      f32x2 t1 = (p2[4] + p2[5]) + (p2[6] + p2[7]);
      f32x2 ts = t0 + t1;
      lrun += ts.x + ts.y;

      // P registers ARE the PV B-fragment (thanks to sw23 K permutation):
      // chunk ks = nb*2+c1, word jj = pk2(p[8c1+2jj], p[8c1+2jj+1])
      union { unsigned u[4]; bf16x8 v; } f0, f1;
      #pragma unroll
      for (int jj = 0; jj < 4; ++jj) {
        f0.u[jj] = pk2(p2[jj].x, p2[jj].y);
        f1.u[jj] = pk2(p2[4 + jj].x, p2[4 + jj].y);
      }
      pa[nb * 2]     = f0.v;
      pa[nb * 2 + 1] = f1.v;
    }

    // o^T += V^T . P^T : A = V^T-frag (row = d), B = P^T-frag (col = m)
    __builtin_amdgcn_s_setprio(1);
    #pragma unroll
    for (int ks = 0; ks < 4; ++ks) {
      bf16x8 vb0 = *(const bf16x8*)(Vc + foff[0][ks]);
      bf16x8 vb1 = *(const bf16x8*)(Vc + foff[1][ks]);
      o0 = __builtin_amdgcn_mfma_f32_32x32x16_bf16(vb0, pa[ks], o0, 0, 0, 0);
      o1 = __builtin_amdgcn_mfma_f32_32x32x16_bf16(vb1, pa[ks], o1, 0, 0, 0);
    }
    __builtin_amdgcn_s_setprio(0);
  }

  // subtract phantom mass of masked n (p=1 each, exactly); fold hi halves.
  // o^T col = m = l31 — lrun is already per-lane aligned with o's column.
  lrun -= (float)(hi ? ch : cl);
  lrun += __shfl_xor(lrun, 32);

  // ---- combine halves + transpose through LDS ----
  __syncthreads();  // all K/V reads done; safe to reuse smem
  float* Ob = (float*)smem;                    // [64 d][128 m] f32 = 32KB
  float* Lb = (float*)(smem + 32768);          // [128] f32

  if (half == 0) {
    #pragma unroll
    for (int r = 0; r < 16; ++r) {
      const int d = (r & 3) + ((r >> 2) << 3) + (hi << 2);
      Ob[d * 128 + wq * 32 + l31]        = o0[r];
      Ob[(d + 32) * 128 + wq * 32 + l31] = o1[r];
    }
    if (hi == 0) Lb[wq * 32 + l31] = lrun;
  }
  __syncthreads();
  if (half == 1) {
    #pragma unroll
    for (int r = 0; r < 16; ++r) {
      const int d = (r & 3) + ((r >> 2) << 3) + (hi << 2);
      Ob[d * 128 + wq * 32 + l31]        += o0[r];
      Ob[(d + 32) * 128 + wq * 32 + l31] += o1[r];
    }
    if (hi == 0) Lb[wq * 32 + l31] += lrun;
  }
  __syncthreads();
  // all 512 threads: transposed read + coalesced float4 stores
  {
    const int m = tid >> 2, dc = (tid & 3) * 16;
    const float lv = Lb[m];
    const float iv = lv > 0.f ? 1.0f / lv : 0.f;
    float* orow = out + ((size_t)(b * M_ + m0 + m)) * D_ + h * DH_ + dc;
    #pragma unroll
    for (int i0 = 0; i0 < 16; i0 += 4) {
      float4 v;
      v.x = Ob[(dc + i0 + 0) * 128 + m] * iv;
      v.y = Ob[(dc + i0 + 1) * 128 + m] * iv;
      v.z = Ob[(dc + i0 + 2) * 128 + m] * iv;
      v.w = Ob[(dc + i0 + 3) * 128 + m] * iv;
      *(float4*)(orow + i0) = v;
    }
  }
}

extern "C" void kernel_launch(void* const* d_in, const int* in_sizes, int n_in,
                              void* d_out, int out_size, void* d_ws, size_t ws_size,
                              hipStream_t stream) {
  const float* q  = (const float*)d_in[0];
  const float* kv = (const float*)d_in[1];
  const int* kv_mask = (const int*)d_in[2];
  float* out = (float*)d_out;

  // ws layout: K' 16MB | Vt 16MB | maskbits 1KB
  bf16_t* kp = (bf16_t*)d_ws;
  bf16_t* vt = kp + (size_t)B_ * H_ * N_ * DH_;
  unsigned long long* mb =
      (unsigned long long*)((char*)d_ws + 2 * (size_t)B_ * H_ * N_ * DH_ * sizeof(bf16_t));

  prep_kernel<<<B_ * 32 * 8, 256, 0, stream>>>(kv, kv_mask, kp, vt, mb);
  attn_kernel<<<B_ * H_ * (M_ / 128), 512, 0, stream>>>(q, kp, vt, mb, out);
}

// Round 5
// 142.717 us; speedup vs baseline: 1.2493x; 1.0296x over previous
//
#include <hip/hip_runtime.h>
#include <hip/hip_bf16.h>
#include <cmath>
#include <stdint.h>

#define B_ 4
#define M_ 1024
#define N_ 2048
#define D_ 1024
#define H_ 16
#define DH_ 64
#define NT 64      // N tile
#define NTH 16     // tiles per half (N split 2-way inside the block)
#define PITCH 72   // prep LDS pitch (bf16)

typedef __bf16 bf16_t;
typedef __attribute__((ext_vector_type(8))) __bf16 bf16x8;
typedef __attribute__((ext_vector_type(16))) float f32x16;
typedef __attribute__((ext_vector_type(2))) float f32x2;

static __device__ __forceinline__ float silu_f(float x) {
  return x / (1.0f + __expf(-x));
}

// pack two f32 -> two bf16 in one u32 (v_cvt_pk_bf16_f32)
static __device__ __forceinline__ unsigned pk2(float a, float b) {
  union { __bf16 h[2]; unsigned u; } p;
  p.h[0] = (__bf16)a; p.h[1] = (__bf16)b;
  return p.u;
}

// async global->LDS, 16B/lane; LDS dest is wave-uniform base + lane*16
static __device__ __forceinline__ void gload16(const bf16_t* g, bf16_t* l) {
  typedef __attribute__((address_space(1))) const unsigned GU;
  typedef __attribute__((address_space(3))) unsigned LU;
  __builtin_amdgcn_global_load_lds((GU*)(const unsigned*)g, (LU*)(unsigned*)l,
                                   16, 0, 0);
}

// swap bits 2 and 3 of a row index (involution) — K-row permutation so the
// QK^T C-layout registers land directly in PV B-fragment order.
static __device__ __forceinline__ int sw23(int x) {
  return (x & ~12) | ((x & 4) << 1) | ((x & 8) >> 1);
}

// ---- prep ----
// K' = L2norm(silu(kv heads)), ZEROED for masked n, written in MFMA A-FRAGMENT
// order: kfrag elem addr = bh*131072 + (tile*8 + nb*4 + kk)*512 +
// (hi*32 + sw23(l31))*8 + j, holding K'[tile*64 + nb*32 + sw23(l31)]
// [kk*16 + hi*8 + j]. attn loads each fragment as ONE coalesced dwordx4.
// Vt = kv^T [bh][d][n] (linear, LDS-staged in attn) — unchanged.
// Mask bits packed for the phantom-mass correction.
__global__ __launch_bounds__(256) void prep_kernel(
    const float* __restrict__ kv, const int* __restrict__ kv_mask,
    bf16_t* __restrict__ kp, bf16_t* __restrict__ vt,
    unsigned long long* __restrict__ mb) {
  __shared__ __align__(16) bf16_t Lt[NT][PITCH];
  const int bx = blockIdx.x;
  const int hp = bx & 7;
  const int nt = (bx >> 3) & 31;
  const int b  = bx >> 8;
  const int n0 = nt * NT;
  const int tid = threadIdx.x;
  const float keep = kv_mask[b * N_ + n0 + (tid >> 2)] ? 0.f : 1.f;

  #pragma unroll
  for (int hi = 0; hi < 2; ++hi) {
    const int h = hp * 2 + hi;
    const size_t bh = (size_t)(b * H_ + h);
    {
      const int r = tid >> 2, c0 = (tid & 3) * 16;
      const float* src = kv + ((size_t)(b * N_ + n0 + r)) * D_ + h * DH_ + c0;
      union { float f[16]; float4 v4[4]; } raw;
      raw.v4[0] = *(const float4*)(src + 0);
      raw.v4[1] = *(const float4*)(src + 4);
      raw.v4[2] = *(const float4*)(src + 8);
      raw.v4[3] = *(const float4*)(src + 12);
      float sv[16];
      float ss = 0.f;
      #pragma unroll
      for (int i = 0; i < 16; ++i) { sv[i] = silu_f(raw.f[i]); ss += sv[i] * sv[i]; }
      ss += __shfl_xor(ss, 1); ss += __shfl_xor(ss, 2);
      const float inv = keep / fmaxf(sqrtf(ss), 1e-6f);  // 0 for masked rows
      union { bf16_t bs[16]; uint4 u[2]; } pk;
      #pragma unroll
      for (int i = 0; i < 16; ++i) pk.bs[i] = (bf16_t)(sv[i] * inv);
      // fragment-order K' write: kk = tid&3, nb = r>>5, lane-row sw23(r&31)
      const size_t fbase = bh * 131072 +
          (size_t)((nt * 8 + (r >> 5) * 4 + (tid & 3)) * 512 + sw23(r & 31) * 8);
      *(uint4*)(kp + fbase)       = pk.u[0];   // hi = 0 (d kk*16 + 0..7)
      *(uint4*)(kp + fbase + 256) = pk.u[1];   // hi = 1 (d kk*16 + 8..15)
      union { bf16_t bs[16]; uint4 u[2]; } pv;
      #pragma unroll
      for (int i = 0; i < 16; ++i) pv.bs[i] = (bf16_t)(raw.f[i] * keep);
      uint4* ldst = (uint4*)&Lt[r][c0];
      ldst[0] = pv.u[0]; ldst[1] = pv.u[1];
    }
    __syncthreads();
    {
      const int d = tid >> 2, nc = (tid & 3) * 16;
      union { bf16_t bs[16]; uint4 u[2]; } pk;
      #pragma unroll
      for (int i = 0; i < 16; ++i) pk.bs[i] = Lt[nc + i][d];
      uint4* dst = (uint4*)(vt + (bh * DH_ + d) * N_ + n0 + nc);
      dst[0] = pk.u[0]; dst[1] = pk.u[1];
    }
    __syncthreads();
  }
  if (bx == 0 && tid < B_ * (N_ / 64)) {
    const int b2 = tid >> 5, tt = tid & 31;
    unsigned long long m = 0ull;
    for (int i = 0; i < 64; ++i)
      if (kv_mask[b2 * N_ + tt * 64 + i]) m |= (1ull << i);
    mb[tid] = m;
  }
}

// ---- main: flash cross-attn, 32x32x16 MFMA. K fragments REGISTER-DIRECT
//      from the frag-layout workspace (one coalesced dwordx4 per fragment,
//      prefetched one tile ahead; L1/L2-resident) — K LDS staging and its
//      ds_reads eliminated. V stays LDS-staged (gload16 ping-pong).
//      Softmax: 2-FMA polynomial e^x ~= 1+x+x^2/2 (|x|<=1/8 folded into Q);
//      masked n algebraic (zeroed K'/V + popcount). 2-way N-split/block. ----
__global__ __launch_bounds__(512, 4) void attn_kernel(
    const float* __restrict__ q, const bf16_t* __restrict__ kp,
    const bf16_t* __restrict__ vt, const unsigned long long* __restrict__ mb,
    float* __restrict__ out) {
  // V[half][buf] at (half*2+buf)*8192 (32KB); epilogue reuses [0,32768) for
  // O^T-partials, Lb at 32768.
  __shared__ __align__(1024) char smem[33280];

  const int tid  = threadIdx.x;
  const int w    = tid >> 6;     // 0..7
  const int wq   = w & 3;        // q-row group
  const int half = w >> 2;       // N-half
  const int lane = tid & 63;
  const int l31  = lane & 31;
  const int hi   = lane >> 5;
  const int rho  = l31 & 7;

  // bijective XCD swizzle (512 wgs % 8 == 0)
  const int wg = (blockIdx.x & 7) * 64 + (blockIdx.x >> 3);
  const int bh = wg >> 3;
  const int m0 = (wg & 7) * 128;
  const int b = bh >> 4, h = bh & 15;

  const bf16_t* vtb = vt + (size_t)bh * DH_ * N_;
  // per-lane K-fragment base: tile stride 4096 elems (8 frags x 512)
  const bf16_t* kfb = kp + (size_t)bh * 131072 + (size_t)half * 65536
                         + (size_t)lane * 8;

  // V staging: wave stages d-rows [wq*16, wq*16+16); source slot-swizzled.
  const int srow  = lane >> 3;
  const int sslot = (lane & 7) ^ srow;
  const bf16_t* vs0 = vtb + (size_t)(wq * 16 + srow) * N_ + half * NTH * NT + sslot * 8;
  const bf16_t* vs1 = vs0 + 8 * N_;

  // prologue: stage V(0); load ka(0) fragments
  {
    bf16_t* Vd = (bf16_t*)(smem + (half * 2 + 0) * 8192) + wq * 16 * NT;
    gload16(vs0, Vd); gload16(vs1, Vd + 512);
  }
  bf16x8 ka[2][4];
  #pragma unroll
  for (int nb = 0; nb < 2; ++nb)
    #pragma unroll
    for (int kk = 0; kk < 4; ++kk)
      ka[nb][kk] = *(const bf16x8*)(kfb + (nb * 4 + kk) * 512);

  // Q: 32 rows/wave straight to registers, pre-scaled by 1/8 (exact 2^-3)
  bf16x8 qb[4];
  {
    const float* qrow =
        q + ((size_t)(b * M_ + m0 + wq * 32 + l31)) * D_ + h * DH_ + hi * 8;
    float sv[32];
    float ss = 0.f;
    #pragma unroll
    for (int kk = 0; kk < 4; ++kk) {
      float4 a0 = *(const float4*)(qrow + kk * 16);
      float4 a1 = *(const float4*)(qrow + kk * 16 + 4);
      sv[kk * 8 + 0] = silu_f(a0.x); sv[kk * 8 + 1] = silu_f(a0.y);
      sv[kk * 8 + 2] = silu_f(a0.z); sv[kk * 8 + 3] = silu_f(a0.w);
      sv[kk * 8 + 4] = silu_f(a1.x); sv[kk * 8 + 5] = silu_f(a1.y);
      sv[kk * 8 + 6] = silu_f(a1.z); sv[kk * 8 + 7] = silu_f(a1.w);
      #pragma unroll
      for (int i = 0; i < 8; ++i) ss += sv[kk * 8 + i] * sv[kk * 8 + i];
    }
    ss += __shfl_xor(ss, 32);
    const float inv = 0.125f / fmaxf(sqrtf(ss), 1e-6f);
    #pragma unroll
    for (int kk = 0; kk < 4; ++kk) {
      union { unsigned u[4]; bf16x8 v; } pq;
      #pragma unroll
      for (int jj = 0; jj < 4; ++jj)
        pq.u[jj] = pk2(sv[kk * 8 + jj * 2] * inv, sv[kk * 8 + jj * 2 + 1] * inv);
      qb[kk] = pq.v;
    }
  }

  // V fragment read offsets: row = i*32+l31, slot' = (2j+hi) ^ (row&7)
  int foff[2][4];
  #pragma unroll
  for (int i = 0; i < 2; ++i)
    #pragma unroll
    for (int j = 0; j < 4; ++j)
      foff[i][j] = (i * 32 + l31) * 64 + ((((j << 1) + hi) ^ rho) << 3);

  f32x16 o0, o1, zvec;
  #pragma unroll
  for (int r = 0; r < 16; ++r) { o0[r] = 0.f; o1[r] = 0.f; zvec[r] = 0.f; }
  float lrun = 0.f;
  unsigned cl = 0, ch = 0;  // masked-n counts for hi=0 / hi=1 lanes
  const unsigned long long* mbb = mb + b * (N_ / 64);

  for (int tt = 0; tt < NTH; ++tt) {
    // barrier: (a) drains V-DMA(tt) + my ka loads (implicit vmcnt(0)),
    // (b) all waves done reading V buf cur^1 -> safe to restage
    __syncthreads();
    const int cur = tt & 1;
    if (tt + 1 < NTH) {
      const int nx = cur ^ 1;
      const size_t vo = (size_t)(tt + 1) * NT;
      bf16_t* Vd = (bf16_t*)(smem + (half * 2 + nx) * 8192) + wq * 16 * NT;
      gload16(vs0 + vo, Vd); gload16(vs1 + vo, Vd + 512);
    }
    // phantom-mass counts (uniform -> SALU popcount); with sw23 permutation
    // lane hi covers n bits {16c + 8*hi + 0..7}.
    const unsigned long long mk = mbb[half * NTH + tt];
    cl += (unsigned)__popcll(mk & 0x00FF00FF00FF00FFULL);
    ch += (unsigned)__popcll(mk & 0xFF00FF00FF00FF00ULL);

    const bf16_t* Vc = (const bf16_t*)(smem + (half * 2 + cur) * 8192);

    bf16x8 pa[4];
    #pragma unroll
    for (int nb = 0; nb < 2; ++nb) {
      // S^T = K'(permuted) . Q'^T : col = l31 (m); reg r of lane hi is
      // n_phys = 16*(r>>3) + 8*hi + (r&7) within this nb 32-block
      __builtin_amdgcn_s_setprio(1);
      f32x16 s = __builtin_amdgcn_mfma_f32_32x32x16_bf16(
          ka[nb][0], qb[0], zvec, 0, 0, 0);
      #pragma unroll
      for (int kk = 1; kk < 4; ++kk)
        s = __builtin_amdgcn_mfma_f32_32x32x16_bf16(ka[nb][kk], qb[kk], s, 0, 0, 0);
      __builtin_amdgcn_s_setprio(0);

      // p = e^x ~= 1 + x + x^2/2 (|x| <= 1/8); poly(0) = 1 EXACTLY
      f32x2 p2[8];
      #pragma unroll
      for (int i = 0; i < 8; ++i) {
        f32x2 x; x.x = s[2 * i]; x.y = s[2 * i + 1];
        f32x2 u = x * 0.5f + 1.0f;
        p2[i] = x * u + 1.0f;
      }
      f32x2 t0 = (p2[0] + p2[1]) + (p2[2] + p2[3]);
      f32x2 t1 = (p2[4] + p2[5]) + (p2[6] + p2[7]);
      f32x2 ts = t0 + t1;
      lrun += ts.x + ts.y;

      // P registers ARE the PV B-fragment (sw23 baked into prep)
      union { unsigned u[4]; bf16x8 v; } f0, f1;
      #pragma unroll
      for (int jj = 0; jj < 4; ++jj) {
        f0.u[jj] = pk2(p2[jj].x, p2[jj].y);
        f1.u[jj] = pk2(p2[4 + jj].x, p2[4 + jj].y);
      }
      pa[nb * 2]     = f0.v;
      pa[nb * 2 + 1] = f1.v;
    }

    // prefetch ka for next tile (wrap at 15 -> in-bounds dummy reload)
    {
      const bf16_t* kn = kfb + (size_t)((tt + 1) & 15) * 4096;
      #pragma unroll
      for (int nb = 0; nb < 2; ++nb)
        #pragma unroll
        for (int kk = 0; kk < 4; ++kk)
          ka[nb][kk] = *(const bf16x8*)(kn + (nb * 4 + kk) * 512);
    }

    // o^T += V^T . P^T : A = V^T-frag (row = d), B = P^T-frag (col = m)
    __builtin_amdgcn_s_setprio(1);
    #pragma unroll
    for (int ks = 0; ks < 4; ++ks) {
      bf16x8 vb0 = *(const bf16x8*)(Vc + foff[0][ks]);
      bf16x8 vb1 = *(const bf16x8*)(Vc + foff[1][ks]);
      o0 = __builtin_amdgcn_mfma_f32_32x32x16_bf16(vb0, pa[ks], o0, 0, 0, 0);
      o1 = __builtin_amdgcn_mfma_f32_32x32x16_bf16(vb1, pa[ks], o1, 0, 0, 0);
    }
    __builtin_amdgcn_s_setprio(0);
  }

  // subtract phantom mass (p=1 per masked n, exact); fold hi halves.
  lrun -= (float)(hi ? ch : cl);
  lrun += __shfl_xor(lrun, 32);

  // ---- combine halves + transpose through LDS ----
  __syncthreads();  // all V reads done; safe to reuse smem
  float* Ob = (float*)smem;                    // [64 d][128 m] f32 = 32KB
  float* Lb = (float*)(smem + 32768);          // [128] f32

  if (half == 0) {
    #pragma unroll
    for (int r = 0; r < 16; ++r) {
      const int d = (r & 3) + ((r >> 2) << 3) + (hi << 2);
      Ob[d * 128 + wq * 32 + l31]        = o0[r];
      Ob[(d + 32) * 128 + wq * 32 + l31] = o1[r];
    }
    if (hi == 0) Lb[wq * 32 + l31] = lrun;
  }
  __syncthreads();
  if (half == 1) {
    #pragma unroll
    for (int r = 0; r < 16; ++r) {
      const int d = (r & 3) + ((r >> 2) << 3) + (hi << 2);
      Ob[d * 128 + wq * 32 + l31]        += o0[r];
      Ob[(d + 32) * 128 + wq * 32 + l31] += o1[r];
    }
    if (hi == 0) Lb[wq * 32 + l31] += lrun;
  }
  __syncthreads();
  // all 512 threads: transposed read + coalesced float4 stores
  {
    const int m = tid >> 2, dc = (tid & 3) * 16;
    const float lv = Lb[m];
    const float iv = lv > 0.f ? 1.0f / lv : 0.f;
    float* orow = out + ((size_t)(b * M_ + m0 + m)) * D_ + h * DH_ + dc;
    #pragma unroll
    for (int i0 = 0; i0 < 16; i0 += 4) {
      float4 v;
      v.x = Ob[(dc + i0 + 0) * 128 + m] * iv;
      v.y = Ob[(dc + i0 + 1) * 128 + m] * iv;
      v.z = Ob[(dc + i0 + 2) * 128 + m] * iv;
      v.w = Ob[(dc + i0 + 3) * 128 + m] * iv;
      *(float4*)(orow + i0) = v;
    }
  }
}

extern "C" void kernel_launch(void* const* d_in, const int* in_sizes, int n_in,
                              void* d_out, int out_size, void* d_ws, size_t ws_size,
                              hipStream_t stream) {
  const float* q  = (const float*)d_in[0];
  const float* kv = (const float*)d_in[1];
  const int* kv_mask = (const int*)d_in[2];
  float* out = (float*)d_out;

  // ws layout: K' frags 16MB | Vt 16MB | maskbits 1KB
  bf16_t* kp = (bf16_t*)d_ws;
  bf16_t* vt = kp + (size_t)B_ * H_ * N_ * DH_;
  unsigned long long* mb =
      (unsigned long long*)((char*)d_ws + 2 * (size_t)B_ * H_ * N_ * DH_ * sizeof(bf16_t));

  prep_kernel<<<B_ * 32 * 8, 256, 0, stream>>>(kv, kv_mask, kp, vt, mb);
  attn_kernel<<<B_ * H_ * (M_ / 128), 512, 0, stream>>>(q, kp, vt, mb, out);
}